// Round 10
// baseline (633.013 us; speedup 1.0000x reference)
//
#include <hip/hip_runtime.h>
#include <hip/hip_bf16.h>
#include <stdint.h>

typedef uint16_t u16;
typedef __attribute__((ext_vector_type(8))) short short8;
typedef __attribute__((ext_vector_type(4))) float floatx4;

#define MFMA(a, b, c) __builtin_amdgcn_mfma_f32_16x16x32_bf16((a), (b), (c), 0, 0, 0)
#define AS1(p) ((const __attribute__((address_space(1))) void*)(p))
#define AS3(p) ((__attribute__((address_space(3))) void*)(p))

static __device__ __forceinline__ float u2f(u16 u) {
    return __uint_as_float(((uint32_t)u) << 16);
}
static __device__ __forceinline__ u16 f2u(float f) {
    union { __hip_bfloat16 h; u16 u; } cv;
    cv.h = __float2bfloat16(f);
    return cv.u;
}
static __device__ __forceinline__ float ldf(const void* p, size_t i, bool f32m) {
    return f32m ? ((const float*)p)[i] : u2f(((const u16*)p)[i]);
}
static __device__ __forceinline__ short8 ld8(const void* p, size_t i, bool f32m) {
    if (f32m) {
        const float* f = (const float*)p + i;
        short8 o;
#pragma unroll
        for (int j = 0; j < 8; ++j) o[j] = (short)f2u(f[j]);
        return o;
    }
    return *reinterpret_cast<const short8*>((const u16*)p + i);
}
static __device__ __forceinline__ void st8(void* p, size_t i, const float* v, bool f32m) {
    if (f32m) {
        float* f = (float*)p + i;
#pragma unroll
        for (int j = 0; j < 8; ++j) f[j] = v[j];
    } else {
        short8 o;
#pragma unroll
        for (int j = 0; j < 8; ++j) o[j] = (short)f2u(v[j]);
        *reinterpret_cast<short8*>((u16*)p + i) = o;
    }
}
// fast GELU (tanh-form via sigmoid); |err| vs erf-GELU ~3e-3 pre-fc2.
static __device__ __forceinline__ float gelu_f(float u) {
    float y = 1.5957691216057308f * (u + 0.044715f * u * u * u);
    return u / (1.f + __expf(-y));
}
// v_permlane32_swap: a' = [a_lo, b_lo], b' = [a_hi, b_hi]
static __device__ __forceinline__ void pl32swap(uint32_t& a, uint32_t& b) {
    asm volatile("v_permlane32_swap_b32 %0, %1" : "+v"(a), "+v"(b));
}

// ---------------------------------------------------------------------------
// Input dtype detector (bf16 N(0,1) never has exponent >= 0xBE).  One block.
// ---------------------------------------------------------------------------
__global__ __launch_bounds__(256) void detect_dtype(const u16* __restrict__ x,
                                                    int* __restrict__ flag)
{
    const int tid = threadIdx.x;
    int cnt = 0;
    for (int i = tid; i < 4096; i += 256) {
        int e = (x[i] >> 7) & 0xFF;
        if (e >= 0xBE) ++cnt;
    }
#pragma unroll
    for (int m = 32; m >= 1; m >>= 1) cnt += __shfl_xor(cnt, m);
    __shared__ int s[4];
    if ((tid & 63) == 0) s[tid >> 6] = cnt;
    __syncthreads();
    if (tid == 0) flag[0] = (s[0] + s[1] + s[2] + s[3] >= 64) ? 1 : 0;
}

// ---------------------------------------------------------------------------
// Transpose src [R][Cc] -> dst [Cc][R-extent] (weights).  MODE 0 plain.
// ---------------------------------------------------------------------------
template <int MODE>
__global__ __launch_bounds__(256) void transpose_k(
    const void* __restrict__ src, void* __restrict__ dst, long dstOff,
    int R, int Cc, int dstS,
    const u16* __restrict__ add,
    const int* __restrict__ dflag, int srcSel, int dstSel)
{
    const bool iF = dflag[0] != 0;
    const bool sF = srcSel && iF;
    const bool dF = dstSel && iF;
    __shared__ __align__(16) u16 tile[64][72];
    const int tid = threadIdx.x;
    const int r0 = blockIdx.y * 64;
    const int c0 = blockIdx.x * 64;
#pragma unroll
    for (int s = 0; s < 2; ++s) {
        int ch = tid + s * 256;
        int ir = ch >> 3, ic = (ch & 7) * 8;
        short8 v = ld8(src, (size_t)(r0 + ir) * Cc + c0 + ic, sF);
#pragma unroll
        for (int j = 0; j < 8; ++j) tile[ir][ic + j] = (u16)v[j];
    }
    __syncthreads();
#pragma unroll
    for (int s = 0; s < 2; ++s) {
        int ch = tid + s * 256;
        int jr = ch >> 3, jc = (ch & 7) * 8;
        float f[8];
#pragma unroll
        for (int j = 0; j < 8; ++j) f[j] = u2f(tile[jc + j][jr]);
        st8(dst, (size_t)dstOff + (size_t)(c0 + jr) * dstS + r0 + jc, f, dF);
    }
}

// ---------------------------------------------------------------------------
// Fused transpose + LayerNorm: x [512][32768] -> img [32768][512] bf16 AND
// xT raw bf16 transposed x (for the proj residual fuse).  R7-proven.
// ---------------------------------------------------------------------------
__global__ __launch_bounds__(256) void tln64(
    const void* __restrict__ x, const void* __restrict__ g, const void* __restrict__ b,
    u16* __restrict__ O, u16* __restrict__ XT, const int* __restrict__ dflag)
{
    const bool iF = dflag[0] != 0;
    __shared__ __align__(16) u16 tile[64][520];
    const int tid = threadIdx.x;
    const int lane = tid & 63, w = tid >> 6;
    const int t0 = blockIdx.x * 64;
    for (int ct = 0; ct < 8; ++ct) {
#pragma unroll
        for (int s = 0; s < 2; ++s) {
            const int ch = tid + s * 256;
            const int ir = ch >> 3;
            const int ic = (ch & 7) * 8;
            const int c = ct * 64 + ir;
            short8 v = ld8(x, (size_t)c * 32768 + t0 + ic, iF);
            const int c8 = c >> 3;
            const int cl = c & 7;
#pragma unroll
            for (int j = 0; j < 8; ++j) {
                const int t = ic + j;
                const int pg = c8 ^ ((t >> 3) & 3);
                tile[t][pg * 8 + cl] = (u16)v[j];
            }
        }
    }
    __syncthreads();
    float gv[8], bv[8];
#pragma unroll
    for (int jj = 0; jj < 8; ++jj) {
        gv[jj] = ldf(g, lane * 8 + jj, iF);
        bv[jj] = ldf(b, lane * 8 + jj, iF);
    }
    for (int tt = 0; tt < 16; ++tt) {
        const int t = w * 16 + tt;
        const int pg = lane ^ ((t >> 3) & 3);
        short8 v = *reinterpret_cast<const short8*>(&tile[t][pg * 8]);
        *reinterpret_cast<short8*>(XT + (size_t)(t0 + t) * 512 + lane * 8) = v;
        float f[8];
        float s = 0.f, sq = 0.f;
#pragma unroll
        for (int jj = 0; jj < 8; ++jj) { f[jj] = u2f((u16)v[jj]); s += f[jj]; sq += f[jj] * f[jj]; }
#pragma unroll
        for (int m = 32; m >= 1; m >>= 1) { s += __shfl_xor(s, m); sq += __shfl_xor(sq, m); }
        const float mean = s * (1.f / 512.f);
        const float var = sq * (1.f / 512.f) - mean * mean;
        const float rstd = rsqrtf(var + 1e-5f);
        short8 o;
#pragma unroll
        for (int jj = 0; jj < 8; ++jj)
            o[jj] = (short)f2u((f[jj] - mean) * rstd * gv[jj] + bv[jj]);
        *reinterpret_cast<short8*>(O + (size_t)(t0 + t) * 512 + lane * 8) = o;
    }
}

// ---------------------------------------------------------------------------
// LN stats only: per-token mean/rstd of X [.][512] -> S as float2.
// ---------------------------------------------------------------------------
__global__ __launch_bounds__(256) void ln_stats(
    const u16* __restrict__ X, float* __restrict__ S)
{
    const int wid = threadIdx.x >> 6, lane = threadIdx.x & 63;
    const int row = blockIdx.x * 4 + wid;
    const size_t base = (size_t)row * 512 + lane * 8;
    short8 v = *reinterpret_cast<const short8*>(X + base);
    float s = 0.f, sq = 0.f;
#pragma unroll
    for (int j = 0; j < 8; ++j) { float f = u2f((u16)v[j]); s += f; sq += f * f; }
#pragma unroll
    for (int m = 32; m >= 1; m >>= 1) { s += __shfl_xor(s, m); sq += __shfl_xor(sq, m); }
    if (lane == 0) {
        const float mean = s * (1.f / 512.f);
        const float var = sq * (1.f / 512.f) - mean * mean;
        float2 st; st.x = mean; st.y = rsqrtf(var + 1e-5f);
        reinterpret_cast<float2*>(S)[row] = st;
    }
}

// ---------------------------------------------------------------------------
// colvec: gw[n] = sum_k g[k]*W[k][n], bw[n] = sum_k b[k]*W[k][n].
// W = fc1_w [512][2048].  Grid 8 x 256 (n coalesced across lanes).
// ---------------------------------------------------------------------------
__global__ __launch_bounds__(256) void colvec(
    const void* __restrict__ W, const void* __restrict__ g, const void* __restrict__ b,
    float* __restrict__ gw, float* __restrict__ bw, const int* __restrict__ dflag)
{
    const bool iF = dflag[0] != 0;
    const int n = blockIdx.x * 256 + threadIdx.x;
    float sg = 0.f, sb = 0.f;
    for (int k = 0; k < 512; ++k) {
        const float wv = ldf(W, (size_t)k * 2048 + n, iF);
        sg += ldf(g, k, iF) * wv;
        sb += ldf(b, k, iF) * wv;
    }
    gw[n] = sg;
    bw[n] = sb;
}

// ---------------------------------------------------------------------------
// scalek: fc1T [2048][512] row-scale by g[k] (k = fast dim).  Grid 512.
// ---------------------------------------------------------------------------
__global__ __launch_bounds__(256) void scalek(
    u16* __restrict__ T, const void* __restrict__ g, const int* __restrict__ dflag)
{
    const bool iF = dflag[0] != 0;
    const size_t i = ((size_t)blockIdx.x * 256 + threadIdx.x) * 8;
    short8 v = *reinterpret_cast<const short8*>(T + i);
    const int k0 = (int)(i & 511);
#pragma unroll
    for (int j = 0; j < 8; ++j) v[j] = (short)f2u(u2f((u16)v[j]) * ldf(g, k0 + j, iF));
    *reinterpret_cast<short8*>(T + i) = v;
}

// ---------------------------------------------------------------------------
// Legacy 128x128 MFMA GEMM (m97 structure) — fc2.  EPI=4: +bias +xf residual
// (token-major) and TRANSPOSED store to out (R6-proven epilogue).
// A split across two buffers at m-tile aSplit (h1c halves in ws).
// ---------------------------------------------------------------------------
template <int EPI>
__global__ __launch_bounds__(256) void gemm_bt(
    const u16* __restrict__ A, const u16* __restrict__ A2, int aSplit,
    const u16* __restrict__ Bt, const void* __restrict__ bias,
    u16* __restrict__ Cout, int Nt, int N, int K,
    const u16* __restrict__ xadd, void* __restrict__ outp, int tokOff,
    const int* __restrict__ dflag)
{
    const bool iF = dflag[0] != 0;
    __shared__ __align__(16) u16 As[2][128 * 32];
    __shared__ __align__(16) u16 Bs[2][128 * 32];
    const int bidf = blockIdx.x;
    const int xcd = bidf & 7;
    const int j = bidf >> 3;
    const int m_blk = (j / Nt) * 8 + xcd;
    const int n_blk = j % Nt;
    const int tid = threadIdx.x;
    const int lane = tid & 63, wid = tid >> 6;
    const int wm = wid >> 1, wn = wid & 1;
    const int quad = lane >> 4, l15 = lane & 15;

    floatx4 zero4 = {0.f, 0.f, 0.f, 0.f};
    floatx4 acc[4][4];
#pragma unroll
    for (int i = 0; i < 4; ++i)
#pragma unroll
        for (int jj = 0; jj < 4; ++jj) acc[i][jj] = zero4;

    const u16* Ab = (A2 && m_blk >= aSplit)
                  ? A2 + (size_t)(m_blk - aSplit) * 128 * K
                  : A + (size_t)m_blk * 128 * K;
    const u16* Bb = Bt + (size_t)n_blk * 128 * K;
    const int r0 = tid >> 2;
    const int k0o = (tid & 3) * 8;

    for (int kk = 0; kk < K; kk += 64) {
        if (kk) __syncthreads();
#pragma unroll
        for (int h = 0; h < 2; ++h) {
            const int kg = kk + h * 32 + k0o;
            char* dA = (char*)As[h] + wid * 1024;
            char* dB = (char*)Bs[h] + wid * 1024;
            __builtin_amdgcn_global_load_lds(AS1(Ab + (size_t)r0 * K + kg),        AS3(dA), 16, 0, 0);
            __builtin_amdgcn_global_load_lds(AS1(Ab + (size_t)(r0 + 64) * K + kg), AS3(dA + 4096), 16, 0, 0);
            __builtin_amdgcn_global_load_lds(AS1(Bb + (size_t)r0 * K + kg),        AS3(dB), 16, 0, 0);
            __builtin_amdgcn_global_load_lds(AS1(Bb + (size_t)(r0 + 64) * K + kg), AS3(dB + 4096), 16, 0, 0);
        }
        __syncthreads();
#pragma unroll
        for (int h = 0; h < 2; ++h) {
            short8 af[4], bfv[4];
#pragma unroll
            for (int i = 0; i < 4; ++i)
                af[i] = *reinterpret_cast<const short8*>(&As[h][(wm * 64 + i * 16 + l15) * 32 + quad * 8]);
#pragma unroll
            for (int jj = 0; jj < 4; ++jj)
                bfv[jj] = *reinterpret_cast<const short8*>(&Bs[h][(wn * 64 + jj * 16 + l15) * 32 + quad * 8]);
#pragma unroll
            for (int i = 0; i < 4; ++i)
#pragma unroll
                for (int jj = 0; jj < 4; ++jj)
                    acc[i][jj] = MFMA(af[i], bfv[jj], acc[i][jj]);
        }
    }

    const int m_base = m_blk * 128 + wm * 64 + quad * 4;
    const int n_base = n_blk * 128 + wn * 64 + l15;
#pragma unroll
    for (int i = 0; i < 4; ++i) {
#pragma unroll
        for (int jj = 0; jj < 4; ++jj) {
            const int n = n_base + jj * 16;
            float badd = 0.f;
            if constexpr (EPI >= 1) badd = ldf(bias, n, iF);
            if constexpr (EPI == 4) {
                float vv[4];
#pragma unroll
                for (int r = 0; r < 4; ++r) {
                    const int m = m_base + i * 16 + r;
                    vv[r] = acc[i][jj][r] + badd + u2f(xadd[(size_t)m * 512 + n]);
                }
                const size_t ob = (size_t)n * 32768 + tokOff + m_base + i * 16;
                if (iF) {
                    floatx4 v4 = {vv[0], vv[1], vv[2], vv[3]};
                    *reinterpret_cast<floatx4*>((float*)outp + ob) = v4;
                } else {
                    union { u16 a[4]; uint2 v; } pk;
#pragma unroll
                    for (int r = 0; r < 4; ++r) pk.a[r] = f2u(vv[r]);
                    *reinterpret_cast<uint2*>((u16*)outp + ob) = pk.v;
                }
            } else {
#pragma unroll
                for (int r = 0; r < 4; ++r) {
                    const int m = m_base + i * 16 + r;
                    float v = acc[i][jj][r] + badd;
                    if constexpr (EPI == 3) v = gelu_f(v);
                    Cout[(size_t)m * N + n] = f2u(v);
                }
            }
        }
    }
}

// ---------------------------------------------------------------------------
// 256x256 8-phase MFMA GEMM (T2+T3+T4+T5, m201-class schedule, plain HIP).
// EPI: 0 none, 2 +bias + token-major residual (proj, R9-proven),
// 5 LN-folded fc1: v = rstd[m]*(acc - mean[m]*gw[n]) + bw[n] + bias[n],
// GELU; output split across Cout/Cout2 at m-tile mSplit.
// ---------------------------------------------------------------------------
#define STG(slot, mat, kh, Gb, kcol) do {                                        \
    char* _d = (char*)&L[(slot)][(mat)][(kh)][0] + ldsofs;                       \
    __builtin_amdgcn_global_load_lds(AS1((Gb) + (size_t)srow0 * K + (kcol) + scol0),         AS3(_d),        16, 0, 0); \
    __builtin_amdgcn_global_load_lds(AS1((Gb) + (size_t)(srow0 + 128) * K + (kcol) + scol0), AS3(_d + 8192), 16, 0, 0); \
} while (0)

#define VMW(n) do { asm volatile("s_waitcnt vmcnt(" #n ")" ::: "memory");        \
                    __builtin_amdgcn_sched_barrier(0); } while (0)

#define PHASE(s, kh, nq, STAGE_STMT, WAIT_STMT) do {                             \
    const char* Au = (const char*)&L[(s)][0][(kh)][0];                           \
    const char* Bu = (const char*)&L[(s)][1][(kh)][0];                           \
    if ((nq) == 0) {                                                             \
        _Pragma("unroll")                                                        \
        for (int mf = 0; mf < 8; ++mf)                                           \
            af[mf] = *reinterpret_cast<const short8*>(Au + aoff[mf]);            \
    }                                                                            \
    short8 b0 = *reinterpret_cast<const short8*>(Bu + boff[nq][0]);              \
    short8 b1 = *reinterpret_cast<const short8*>(Bu + boff[nq][1]);              \
    STAGE_STMT;                                                                  \
    asm volatile("s_barrier" ::: "memory");                                      \
    asm volatile("s_waitcnt lgkmcnt(0)" ::: "memory");                           \
    __builtin_amdgcn_sched_barrier(0);                                           \
    __builtin_amdgcn_s_setprio(1);                                               \
    _Pragma("unroll")                                                            \
    for (int mf = 0; mf < 8; ++mf) {                                             \
        acc[mf][(nq) * 2]     = MFMA(af[mf], b0, acc[mf][(nq) * 2]);             \
        acc[mf][(nq) * 2 + 1] = MFMA(af[mf], b1, acc[mf][(nq) * 2 + 1]);         \
    }                                                                            \
    __builtin_amdgcn_s_setprio(0);                                               \
    WAIT_STMT;                                                                   \
    asm volatile("s_barrier" ::: "memory");                                      \
} while (0)

#define GROUP(g, W2, W4, S12, S34) do {                                          \
    const int _s = (g) & 1;                                                      \
    PHASE(_s, 0, 0, if (S12) STG(_s ^ 1, 0, 1, Ab, ((g) + 1) * 64 + 32), (void)0); \
    PHASE(_s, 0, 1, if (S12) STG(_s ^ 1, 1, 1, Bb, ((g) + 1) * 64 + 32), W2);    \
    PHASE(_s, 1, 0, if (S34) STG(_s,     0, 0, Ab, ((g) + 2) * 64),      (void)0); \
    PHASE(_s, 1, 1, if (S34) STG(_s,     1, 0, Bb, ((g) + 2) * 64),      W4);    \
} while (0)

template <int EPI>
__global__ __launch_bounds__(512, 2) void gemm256_bt(
    const u16* __restrict__ A, const u16* __restrict__ Bt,
    const void* __restrict__ bias,
    u16* __restrict__ Cout, u16* __restrict__ Cout2, int mSplit,
    int Nt, int N, int K,
    const u16* __restrict__ xadd,
    const float* __restrict__ s2, const float* __restrict__ gwv,
    const float* __restrict__ bwv,
    const int* __restrict__ dflag)
{
    const bool iF = dflag[0] != 0;
    __shared__ __align__(16) u16 L[2][2][2][8192];   // [slot][A/B][kh][256*32]
    const int bidf = blockIdx.x;
    const int xcd = bidf & 7;
    const int j = bidf >> 3;
    const int m_blk = (j / Nt) * 8 + xcd;
    const int n_blk = j % Nt;
    const int tid = threadIdx.x;
    const int lane = tid & 63, wid = tid >> 6;
    const int wm = wid >> 2, wn = wid & 3;
    const int quad = lane >> 4, l15 = lane & 15;

    const int srow0 = wid * 16 + (lane >> 2);
    const int scol0 = ((lane & 3) ^ ((srow0 >> 1) & 3)) * 8;
    const int ldsofs = wid * 1024;

    const u16* Ab = A + (size_t)m_blk * 256 * K;
    const u16* Bb = Bt + (size_t)n_blk * 256 * K;

    const int sq = (quad ^ ((l15 >> 1) & 3)) << 4;
    int aoff[8], boff[2][2];
#pragma unroll
    for (int mf = 0; mf < 8; ++mf)
        aoff[mf] = (wm * 128 + mf * 16 + l15) * 64 + sq;
#pragma unroll
    for (int nq = 0; nq < 2; ++nq)
#pragma unroll
        for (int jj = 0; jj < 2; ++jj)
            boff[nq][jj] = (wn * 64 + nq * 32 + jj * 16 + l15) * 64 + sq;

    floatx4 zero4 = {0.f, 0.f, 0.f, 0.f};
    floatx4 acc[8][4];
#pragma unroll
    for (int i = 0; i < 8; ++i)
#pragma unroll
        for (int jj = 0; jj < 4; ++jj) acc[i][jj] = zero4;
    short8 af[8];

    const int NG = K >> 6;

    STG(0, 0, 0, Ab, 0);
    STG(0, 1, 0, Bb, 0);
    STG(0, 0, 1, Ab, 32);
    STG(0, 1, 1, Bb, 32);
    STG(1, 0, 0, Ab, 64);
    STG(1, 1, 0, Bb, 64);
    VMW(8);
    asm volatile("s_barrier" ::: "memory");

    int g = 0;
    for (; g < NG - 2; ++g) GROUP(g, VMW(8), VMW(8), true, true);
    GROUP(g, VMW(8), VMW(4), true, false); ++g;
    GROUP(g, VMW(0), (void)0, false, false);

    u16* Co = Cout;
    int mOff = 0;
    if (EPI == 5 && Cout2 && m_blk >= mSplit) { Co = Cout2; mOff = mSplit * 256; }

    const int m0 = m_blk * 256 + wm * 128 + quad * 4;
    const int n0 = n_blk * 256 + wn * 64 + l15;
#pragma unroll
    for (int mf = 0; mf < 8; ++mf) {
        float mn[4], rs[4];
        if constexpr (EPI == 5) {
#pragma unroll
            for (int r = 0; r < 4; ++r) {
                const float2 st = reinterpret_cast<const float2*>(s2)[m0 + mf * 16 + r];
                mn[r] = st.x; rs[r] = st.y;
            }
        }
#pragma unroll
        for (int nf = 0; nf < 4; ++nf) {
            const int n = n0 + nf * 16;
            float badd = 0.f;
            if constexpr (EPI >= 1) badd = ldf(bias, n, iF);
            float gwn = 0.f, bwn = 0.f;
            if constexpr (EPI == 5) { gwn = gwv[n]; bwn = bwv[n]; }
#pragma unroll
            for (int r = 0; r < 4; ++r) {
                const int m = m0 + mf * 16 + r;
                float v;
                if constexpr (EPI == 5) {
                    v = rs[r] * (acc[mf][nf][r] - mn[r] * gwn) + bwn + badd;
                    v = gelu_f(v);
                } else {
                    v = acc[mf][nf][r] + badd;
                    if constexpr (EPI == 2) v += u2f(xadd[(size_t)m * 512 + n]);
                }
                Co[(size_t)(m - mOff) * N + n] = f2u(v);
            }
        }
    }
}

// ---------------------------------------------------------------------------
// CSWin window attention + fused LEPE (R10 structure, unchanged).
// ---------------------------------------------------------------------------
__global__ __launch_bounds__(256) void cswin_attn(
    const u16* __restrict__ qkv,
    const void* __restrict__ lepe0_w, const void* __restrict__ lepe0_b,
    const void* __restrict__ lepe1_w, const void* __restrict__ lepe1_b,
    u16* __restrict__ att, const int* __restrict__ dflag)
{
    const bool iF = dflag[0] != 0;
    __shared__ __align__(16) u16 q_s[4096];
    __shared__ __align__(16) u16 k_s[4096];
    __shared__ __align__(16) u16 vt_s[32 * 130];
    __shared__ float lw_s[32 * 9];
    __shared__ float lb_s[32];

    const int bid = blockIdx.x;
    const int branch = bid >> 11;
    const int rr = bid & 2047;
    const int win = rr >> 3, head = rr & 7;
    const int d = win >> 3, blk = win & 7;
    const int tid = threadIdx.x;
    const int lane = tid & 63, wid = tid >> 6;
    const int quad = lane >> 4, l15 = lane & 15;
    const int choff = branch * 256 + head * 32;
    const int dbase = d * 1024;

    const void* lw = branch ? lepe1_w : lepe0_w;
    const void* lbp = branch ? lepe1_b : lepe0_b;
    for (int i = tid; i < 288; i += 256) lw_s[i] = ldf(lw, head * 288 + i, iF);
    if (tid < 32) lb_s[tid] = ldf(lbp, head * 32 + tid, iF);

#pragma unroll
    for (int s = 0; s < 2; ++s) {
        int ch = tid + s * 256;
        int t = ch >> 2, e0 = (ch & 3) * 8;
        int l = branch ? (dbase + blk * 128 + t)
                       : (dbase + (t >> 2) * 32 + blk * 4 + (t & 3));
        size_t rowo = (size_t)l * 1536 + choff + e0;
        short8 qv = *reinterpret_cast<const short8*>(qkv + rowo);
        short8 kv = *reinterpret_cast<const short8*>(qkv + rowo + 512);
        short8 vv = *reinterpret_cast<const short8*>(qkv + rowo + 1024);
        const int sw = ((ch >> 3) & 3) << 3;     // row=ch>>2: ((row>>1)&3)<<3
        *reinterpret_cast<short8*>(&q_s[(ch * 8) ^ sw]) = qv;
        *reinterpret_cast<short8*>(&k_s[(ch * 8) ^ sw]) = kv;
#pragma unroll
        for (int j = 0; j < 8; ++j) vt_s[(e0 + j) * 130 + t] = (u16)vv[j];
    }
    __syncthreads();

    // ---- QK^T swapped: st[kt][qi] = St[k-tile kt][q-tile wid*2+qi] ----
    floatx4 zero4 = {0.f, 0.f, 0.f, 0.f};
    const int sq8 = (quad ^ ((l15 >> 1) & 3)) * 8;   // swizzled k-slot (u16)
    short8 qf[2];
#pragma unroll
    for (int qi = 0; qi < 2; ++qi)
        qf[qi] = *reinterpret_cast<const short8*>(&q_s[(wid * 32 + qi * 16 + l15) * 32 + sq8]);
    floatx4 st[8][2];
#pragma unroll
    for (int kt = 0; kt < 8; ++kt) { st[kt][0] = zero4; st[kt][1] = zero4; }
#pragma unroll
    for (int kt = 0; kt < 8; ++kt) {
        short8 kf = *reinterpret_cast<const short8*>(&k_s[(kt * 16 + l15) * 32 + sq8]);
        st[kt][0] = MFMA(kf, qf[0], st[kt][0]);
        st[kt][1] = MFMA(kf, qf[1], st[kt][1]);
    }
    // lane (quad,l15): st[kt][qi][r] = S[q = wid*32+qi*16+l15][k = kt*16+quad*4+r]

    // ---- softmax: lane-local over 32 regs + cross-quad reduce ----
    const float scale = 0.17677669529663687f;
    float inv[2];
#pragma unroll
    for (int qi = 0; qi < 2; ++qi) {
        float sum = 0.f;
#pragma unroll
        for (int kt = 0; kt < 8; ++kt)
#pragma unroll
            for (int r = 0; r < 4; ++r) {
                float v = __expf(st[kt][qi][r] * scale);
                st[kt][qi][r] = v;
                sum += v;
            }
        sum += __shfl_xor(sum, 16);
        sum += __shfl_xor(sum, 32);
        inv[qi] = 1.f / sum;
    }
    // pack P to bf16 pairs: pk[qi][kt][u] = (k even -> lo16)
    uint32_t pk[2][8][2];
#pragma unroll
    for (int qi = 0; qi < 2; ++qi)
#pragma unroll
        for (int kt = 0; kt < 8; ++kt)
#pragma unroll
            for (int u = 0; u < 2; ++u)
                pk[qi][kt][u] = (uint32_t)f2u(st[kt][qi][2 * u] * inv[qi])
                              | ((uint32_t)f2u(st[kt][qi][2 * u + 1] * inv[qi]) << 16);
    // stage 1 (xor-32): even slot -> A1 (from b5s=0 lane), odd slot -> B1
#pragma unroll
    for (int qi = 0; qi < 2; ++qi)
#pragma unroll
        for (int t = 0; t < 4; ++t)
#pragma unroll
            for (int u = 0; u < 2; ++u)
                pl32swap(pk[qi][2 * t][u], pk[qi][2 * t + 1][u]);

    // ---- PV: A-frag assembled in-register (stage 2: xor-16 + select) ----
    const uint32_t* v32 = (const uint32_t*)vt_s;
    const int hi4 = (lane >> 4) & 1;                  // lane bit4
    floatx4 oacc[2][2];
#pragma unroll
    for (int qi = 0; qi < 2; ++qi) { oacc[qi][0] = zero4; oacc[qi][1] = zero4; }
#pragma unroll
    for (int ks = 0; ks < 4; ++ks) {
        const int kq = ks * 16 + quad * 4;
        union { uint32_t w[4]; short8 s; } bv[2];
#pragma unroll
        for (int j = 0; j < 2; ++j) {
            const int chan = j * 16 + l15;
#pragma unroll
            for (int q = 0; q < 4; ++q) bv[j].w[q] = v32[chan * 65 + kq + q];
        }
#pragma unroll
        for (int qi = 0; qi < 2; ++qi) {
            const uint32_t a0 = pk[qi][2 * ks][0],     a1 = pk[qi][2 * ks][1];
            const uint32_t b0 = pk[qi][2 * ks + 1][0], b1 = pk[qi][2 * ks + 1][1];
            const uint32_t s0 = (uint32_t)__shfl_xor((int)a0, 16);
            const uint32_t s1 = (uint32_t)__shfl_xor((int)a1, 16);
            const uint32_t t0 = (uint32_t)__shfl_xor((int)b0, 16);
            const uint32_t t1 = (uint32_t)__shfl_xor((int)b1, 16);
            union { uint32_t w[4]; short8 s; } gw;
            gw.w[0] = hi4 ? t0 : a0;
            gw.w[1] = hi4 ? t1 : a1;
            gw.w[2] = hi4 ? b0 : s0;
            gw.w[3] = hi4 ? b1 : s1;
            oacc[qi][0] = MFMA(gw.s, bv[0].s, oacc[qi][0]);
            oacc[qi][1] = MFMA(gw.s, bv[1].s, oacc[qi][1]);
        }
    }
    // oacc[qi][j][r] = O[q = wid*32+qi*16+quad*4+r][ch = j*16+l15]

    // ---- LEPE epilogue: shared clamped b32 span loads per (ii,j,dy) ----
    const int Hs = branch ? 4 : 32;
    const int Wsz = branch ? 32 : 4;
    const int wsl = branch ? 5 : 2;
    const int wmask = Wsz - 1;
#pragma unroll
    for (int ii = 0; ii < 2; ++ii) {
        const int t0 = wid * 32 + ii * 16 + quad * 4;  // token of r=0
        const int hi0 = t0 >> wsl;
        const int w0 = t0 & wmask;
        const int y0 = (hi0 > 0) ? -1 : 0;
        const int y1 = (hi0 < Hs - 1) ? 1 : 0;
        const bool xm = (w0 > 0);
        const bool xp = (w0 + 4 < Wsz);
#pragma unroll
        for (int j = 0; j < 2; ++j) {
            const int e = j * 16 + l15;
            float val[4];
#pragma unroll
            for (int r = 0; r < 4; ++r) val[r] = oacc[ii][j][r] + lb_s[e];
            const uint32_t* vrow = v32 + e * 65;
            const float* wrow = &lw_s[e * 9];
            for (int dy = y0; dy <= y1; ++dy) {
                const int rowb = (hi0 + dy) << wsl;   // token base of conv row
                const int wlo = rowb >> 1;
                const int whi = wlo + (Wsz >> 1) - 1;
                const int wb = wlo + (w0 >> 1);       // word (w0, w0+1)
                int c0 = wb - 1; if (c0 < wlo) c0 = wlo;
                int c3 = wb + 2; if (c3 > whi) c3 = whi;
                const uint32_t u0 = vrow[c0];
                const uint32_t u1 = vrow[wb];
                const uint32_t u2 = vrow[wb + 1];
                const uint32_t u3 = vrow[c3];
                const float em1 = __uint_as_float(u0 & 0xffff0000u);
                const float f0 = __uint_as_float(u1 << 16);
                const float f1 = __uint_as_float(u1 & 0xffff0000u);
                const float f2 = __uint_as_float(u2 << 16);
                const float f3 = __uint_as_float(u2 & 0xffff0000u);
                const float f4 = __uint_as_float(u3 << 16);
                const float* w3 = wrow + (dy + 1) * 3;
                const float wl = w3[0], wc = w3[1], wp = w3[2];
                const float wl0 = xm ? wl : 0.f;
                const float wp3 = xp ? wp : 0.f;
                val[0] += wl0 * em1 + wc * f0 + wp * f1;
                val[1] += wl * f0 + wc * f1 + wp * f2;
                val[2] += wl * f1 + wc * f2 + wp * f3;
                val[3] += wl * f2 + wc * f3 + wp3 * f4;
            }
#pragma unroll
            for (int r = 0; r < 4; ++r) {
                const int t = t0 + r;
                const int l = branch ? (dbase + blk * 128 + t)
                                     : (dbase + (t >> 2) * 32 + blk * 4 + (t & 3));
                att[(size_t)l * 512 + choff + e] = f2u(val[r]);
            }
        }
    }
}

// ---------------------------------------------------------------------------
// Launch.  Workspace 104 MiB:
//   [0,2) qkvT [2,3) projT [3,5) fc1T [5,7) fc2T
//   [7,8): flag @+0, gw @+4K, bw @+16K, stats(float2 x 32768) @+32K
//   h1cA [8,40)   xf [40,72)   h1cB [72,104)   (qkvb [8,104) dead after attn)
//   d_out overlay: img [0,32) + xT [32,64) (dead after proj); final out
//   written by fc2 EPI=4 (residual + transposed store) directly.
//   LN2 folded into fc1: stats + scaled fc1T + gw/bw (colvec).
// ---------------------------------------------------------------------------
extern "C" void kernel_launch(void* const* d_in, const int* in_sizes, int n_in,
                              void* d_out, int out_size, void* d_ws, size_t ws_size,
                              hipStream_t stream)
{
    const void* x      = d_in[0];
    const void* n1g    = d_in[1];
    const void* n1b    = d_in[2];
    const void* qkv_w  = d_in[3];
    const void* l0w    = d_in[4];
    const void* l0b    = d_in[5];
    const void* l1w    = d_in[6];
    const void* l1b    = d_in[7];
    const void* proj_w = d_in[8];
    const void* proj_b = d_in[9];
    const void* n2g    = d_in[10];
    const void* n2b    = d_in[11];
    const void* fc1_w  = d_in[12];
    const void* fc1_b  = d_in[13];
    const void* fc2_w  = d_in[14];
    const void* fc2_b  = d_in[15];

    const size_t MB = 1ull << 20;
    if (ws_size < 104 * MB) return;

    char* w = (char*)d_ws;
    u16* qkvT  = (u16*)(w + 0 * MB);
    u16* projT = (u16*)(w + 2 * MB);
    u16* fc1T  = (u16*)(w + 3 * MB);
    u16* fc2T  = (u16*)(w + 5 * MB);
    int* flag  = (int*)(w + 7 * MB);
    float* gw  = (float*)(w + 7 * MB + 4096);
    float* bw  = (float*)(w + 7 * MB + 16384);
    float* stats = (float*)(w + 7 * MB + 32768);
    u16* qkvb  = (u16*)(w + 8 * MB);    // [8,104) dead after attn
    u16* h1cA  = (u16*)(w + 8 * MB);    // [8,40)  rows 0..8191
    u16* xf    = (u16*)(w + 40 * MB);   // [40,72)
    u16* h1cB  = (u16*)(w + 72 * MB);   // [72,104) rows 8192..16383
    u16* img   = (u16*)d_out;                       // d_out [0,32)
    u16* xT    = (u16*)d_out + 16777216;            // d_out [32,64)
    u16* attb  = (u16*)d_out;                       // d_out [0,32)

    const dim3 B(256);
    const dim3 B512(512);
    const u16* NUL = nullptr;
    u16* NULN = nullptr;
    const void* NULV = nullptr;
    const float* NULF = nullptr;

    detect_dtype<<<dim3(1), B, 0, stream>>>((const u16*)x, flag);

    // weight transposes to [N][K]
    transpose_k<0><<<dim3(24, 8), B, 0, stream>>>(qkv_w, qkvT, 0, 512, 1536, 512, NUL, flag, 1, 0);
    transpose_k<0><<<dim3(8, 8),  B, 0, stream>>>(proj_w, projT, 0, 512, 512, 512, NUL, flag, 1, 0);
    transpose_k<0><<<dim3(32, 8), B, 0, stream>>>(fc1_w, fc1T, 0, 512, 2048, 512, NUL, flag, 1, 0);
    transpose_k<0><<<dim3(8, 32), B, 0, stream>>>(fc2_w, fc2T, 0, 2048, 512, 2048, NUL, flag, 1, 0);
    // LN-fold precompute: fc1T *= g[k] rows; gw/bw column sums
    scalek<<<dim3(512), B, 0, stream>>>(fc1T, n2g, flag);
    colvec<<<dim3(8), B, 0, stream>>>(fc1_w, n2g, n2b, gw, bw, flag);

    // fused transpose + LN1: x -> img [0,32) AND raw xT [32,64) (both bf16)
    tln64<<<dim3(512), B, 0, stream>>>(x, n1g, n1b, img, xT, flag);

    // qkv = img @ qkv_w   [32768][1536]   Mt=128, Nt=6
    gemm256_bt<0><<<dim3(128 * 6), B512, 0, stream>>>(img, qkvT, NULV, qkvb, NULN, 0, 6, 1536, 512, NUL, NULF, NULF, NULF, flag);

    cswin_attn<<<dim3(4096), B, 0, stream>>>(qkvb, l0w, l0b, l1w, l1b, attb, flag);

    // xf = att @ proj_w + proj_b + xT   (fused token-major residual)
    gemm256_bt<2><<<dim3(128 * 2), B512, 0, stream>>>(attb, projT, proj_b, xf, NULN, 0, 2, 512, 512, xT, NULF, NULF, NULF, flag);

    // LN2 stats for all tokens (mean,rstd per token of xf)
    ln_stats<<<dim3(8192), B, 0, stream>>>(xf, stats);

    // MLP in 2 chunks of 16384 tokens; LN folded into fc1; fc2 fuses +xf
    // residual and transposed store straight into d_out.
    for (int i = 0; i < 2; ++i) {
        const int tok0 = i * 16384;
        const size_t off = (size_t)tok0 * 512;
        gemm256_bt<5><<<dim3(64 * 8), B512, 0, stream>>>(xf + off, fc1T, fc1_b,
            h1cA, h1cB, 32, 8, 2048, 512, NUL,
            stats + (size_t)tok0 * 2, gw, bw, flag);
        gemm_bt<4><<<dim3(128 * 4), B, 0, stream>>>(h1cA, h1cB, 64, fc2T, fc2_b,
            NULN, 4, 512, 2048, xf + off, d_out, tok0, flag);
    }
}

// Round 11
// 541.932 us; speedup vs baseline: 1.1681x; 1.1681x over previous
//
#include <hip/hip_runtime.h>
#include <hip/hip_bf16.h>
#include <stdint.h>

typedef uint16_t u16;
typedef __attribute__((ext_vector_type(8))) short short8;
typedef __attribute__((ext_vector_type(4))) float floatx4;

#define MFMA(a, b, c) __builtin_amdgcn_mfma_f32_16x16x32_bf16((a), (b), (c), 0, 0, 0)
#define AS1(p) ((const __attribute__((address_space(1))) void*)(p))
#define AS3(p) ((__attribute__((address_space(3))) void*)(p))

static __device__ __forceinline__ float u2f(u16 u) {
    return __uint_as_float(((uint32_t)u) << 16);
}
static __device__ __forceinline__ u16 f2u(float f) {
    union { __hip_bfloat16 h; u16 u; } cv;
    cv.h = __float2bfloat16(f);
    return cv.u;
}
static __device__ __forceinline__ float ldf(const void* p, size_t i, bool f32m) {
    return f32m ? ((const float*)p)[i] : u2f(((const u16*)p)[i]);
}
static __device__ __forceinline__ short8 ld8(const void* p, size_t i, bool f32m) {
    if (f32m) {
        const float* f = (const float*)p + i;
        short8 o;
#pragma unroll
        for (int j = 0; j < 8; ++j) o[j] = (short)f2u(f[j]);
        return o;
    }
    return *reinterpret_cast<const short8*>((const u16*)p + i);
}
static __device__ __forceinline__ void st8(void* p, size_t i, const float* v, bool f32m) {
    if (f32m) {
        float* f = (float*)p + i;
#pragma unroll
        for (int j = 0; j < 8; ++j) f[j] = v[j];
    } else {
        short8 o;
#pragma unroll
        for (int j = 0; j < 8; ++j) o[j] = (short)f2u(v[j]);
        *reinterpret_cast<short8*>((u16*)p + i) = o;
    }
}
// fast GELU (tanh-form via sigmoid); |err| vs erf-GELU ~3e-3 pre-fc2.
static __device__ __forceinline__ float gelu_f(float u) {
    float y = 1.5957691216057308f * (u + 0.044715f * u * u * u);
    return u / (1.f + __expf(-y));
}
// v_permlane32_swap: a' = [a_lo, b_lo], b' = [a_hi, b_hi]
static __device__ __forceinline__ void pl32swap(uint32_t& a, uint32_t& b) {
    asm volatile("v_permlane32_swap_b32 %0, %1" : "+v"(a), "+v"(b));
}

// ---------------------------------------------------------------------------
// Input dtype detector (bf16 N(0,1) never has exponent >= 0xBE).  One block.
// ---------------------------------------------------------------------------
__global__ __launch_bounds__(256) void detect_dtype(const u16* __restrict__ x,
                                                    int* __restrict__ flag)
{
    const int tid = threadIdx.x;
    int cnt = 0;
    for (int i = tid; i < 4096; i += 256) {
        int e = (x[i] >> 7) & 0xFF;
        if (e >= 0xBE) ++cnt;
    }
#pragma unroll
    for (int m = 32; m >= 1; m >>= 1) cnt += __shfl_xor(cnt, m);
    __shared__ int s[4];
    if ((tid & 63) == 0) s[tid >> 6] = cnt;
    __syncthreads();
    if (tid == 0) flag[0] = (s[0] + s[1] + s[2] + s[3] >= 64) ? 1 : 0;
}

// ---------------------------------------------------------------------------
// Transpose src [R][Cc] -> dst [Cc][R-extent] (weights).  MODE 0 plain.
// ---------------------------------------------------------------------------
template <int MODE>
__global__ __launch_bounds__(256) void transpose_k(
    const void* __restrict__ src, void* __restrict__ dst, long dstOff,
    int R, int Cc, int dstS,
    const u16* __restrict__ add,
    const int* __restrict__ dflag, int srcSel, int dstSel)
{
    const bool iF = dflag[0] != 0;
    const bool sF = srcSel && iF;
    const bool dF = dstSel && iF;
    __shared__ __align__(16) u16 tile[64][72];
    const int tid = threadIdx.x;
    const int r0 = blockIdx.y * 64;
    const int c0 = blockIdx.x * 64;
#pragma unroll
    for (int s = 0; s < 2; ++s) {
        int ch = tid + s * 256;
        int ir = ch >> 3, ic = (ch & 7) * 8;
        short8 v = ld8(src, (size_t)(r0 + ir) * Cc + c0 + ic, sF);
#pragma unroll
        for (int j = 0; j < 8; ++j) tile[ir][ic + j] = (u16)v[j];
    }
    __syncthreads();
#pragma unroll
    for (int s = 0; s < 2; ++s) {
        int ch = tid + s * 256;
        int jr = ch >> 3, jc = (ch & 7) * 8;
        float f[8];
#pragma unroll
        for (int j = 0; j < 8; ++j) f[j] = u2f(tile[jc + j][jr]);
        st8(dst, (size_t)dstOff + (size_t)(c0 + jr) * dstS + r0 + jc, f, dF);
    }
}

// ---------------------------------------------------------------------------
// Fused transpose + LayerNorm: x [512][32768] -> img [32768][512] bf16 AND
// xT raw bf16 transposed x (for the proj residual fuse).  R7-proven.
// ---------------------------------------------------------------------------
__global__ __launch_bounds__(256) void tln64(
    const void* __restrict__ x, const void* __restrict__ g, const void* __restrict__ b,
    u16* __restrict__ O, u16* __restrict__ XT, const int* __restrict__ dflag)
{
    const bool iF = dflag[0] != 0;
    __shared__ __align__(16) u16 tile[64][520];
    const int tid = threadIdx.x;
    const int lane = tid & 63, w = tid >> 6;
    const int t0 = blockIdx.x * 64;
    for (int ct = 0; ct < 8; ++ct) {
#pragma unroll
        for (int s = 0; s < 2; ++s) {
            const int ch = tid + s * 256;
            const int ir = ch >> 3;
            const int ic = (ch & 7) * 8;
            const int c = ct * 64 + ir;
            short8 v = ld8(x, (size_t)c * 32768 + t0 + ic, iF);
            const int c8 = c >> 3;
            const int cl = c & 7;
#pragma unroll
            for (int j = 0; j < 8; ++j) {
                const int t = ic + j;
                const int pg = c8 ^ ((t >> 3) & 3);
                tile[t][pg * 8 + cl] = (u16)v[j];
            }
        }
    }
    __syncthreads();
    float gv[8], bv[8];
#pragma unroll
    for (int jj = 0; jj < 8; ++jj) {
        gv[jj] = ldf(g, lane * 8 + jj, iF);
        bv[jj] = ldf(b, lane * 8 + jj, iF);
    }
    for (int tt = 0; tt < 16; ++tt) {
        const int t = w * 16 + tt;
        const int pg = lane ^ ((t >> 3) & 3);
        short8 v = *reinterpret_cast<const short8*>(&tile[t][pg * 8]);
        *reinterpret_cast<short8*>(XT + (size_t)(t0 + t) * 512 + lane * 8) = v;
        float f[8];
        float s = 0.f, sq = 0.f;
#pragma unroll
        for (int jj = 0; jj < 8; ++jj) { f[jj] = u2f((u16)v[jj]); s += f[jj]; sq += f[jj] * f[jj]; }
#pragma unroll
        for (int m = 32; m >= 1; m >>= 1) { s += __shfl_xor(s, m); sq += __shfl_xor(sq, m); }
        const float mean = s * (1.f / 512.f);
        const float var = sq * (1.f / 512.f) - mean * mean;
        const float rstd = rsqrtf(var + 1e-5f);
        short8 o;
#pragma unroll
        for (int jj = 0; jj < 8; ++jj)
            o[jj] = (short)f2u((f[jj] - mean) * rstd * gv[jj] + bv[jj]);
        *reinterpret_cast<short8*>(O + (size_t)(t0 + t) * 512 + lane * 8) = o;
    }
}

// ---------------------------------------------------------------------------
// LN stats only: per-token mean/rstd of X [.][512] -> S as float2.
// ---------------------------------------------------------------------------
__global__ __launch_bounds__(256) void ln_stats(
    const u16* __restrict__ X, float* __restrict__ S)
{
    const int wid = threadIdx.x >> 6, lane = threadIdx.x & 63;
    const int row = blockIdx.x * 4 + wid;
    const size_t base = (size_t)row * 512 + lane * 8;
    short8 v = *reinterpret_cast<const short8*>(X + base);
    float s = 0.f, sq = 0.f;
#pragma unroll
    for (int j = 0; j < 8; ++j) { float f = u2f((u16)v[j]); s += f; sq += f * f; }
#pragma unroll
    for (int m = 32; m >= 1; m >>= 1) { s += __shfl_xor(s, m); sq += __shfl_xor(sq, m); }
    if (lane == 0) {
        const float mean = s * (1.f / 512.f);
        const float var = sq * (1.f / 512.f) - mean * mean;
        float2 st; st.x = mean; st.y = rsqrtf(var + 1e-5f);
        reinterpret_cast<float2*>(S)[row] = st;
    }
}

// ---------------------------------------------------------------------------
// scalecol: one wave per column n of fc1T [2048][512] (k fast).
// Reads the wave's 512 k's coalesced (short8/lane), computes BOTH
// gw[n] = sum_k g[k]*W[k][n]  (sum of the scaled weights the MFMA will use)
// and bw[n] = sum_k b[k]*W[k][n], scales fc1T in place, shfl-reduces,
// lane 0 writes.  Grid 512 x 256 (4 waves = 4 n per block).
// Replaces R10's scalek + 8-block latency-serial colvec (111 us!).
// ---------------------------------------------------------------------------
__global__ __launch_bounds__(256) void scalecol(
    u16* __restrict__ T, const void* __restrict__ g, const void* __restrict__ b,
    float* __restrict__ gw, float* __restrict__ bw, const int* __restrict__ dflag)
{
    const bool iF = dflag[0] != 0;
    const int lane = threadIdx.x & 63, wv = threadIdx.x >> 6;
    const int n = blockIdx.x * 4 + wv;
    const int k0 = lane * 8;
    const size_t base = (size_t)n * 512 + k0;
    short8 v = *reinterpret_cast<const short8*>(T + base);
    float sg = 0.f, sb = 0.f;
    short8 o;
#pragma unroll
    for (int j = 0; j < 8; ++j) {
        const float wvv = u2f((u16)v[j]);
        const float sc = wvv * ldf(g, k0 + j, iF);
        sg += sc;
        sb += wvv * ldf(b, k0 + j, iF);
        o[j] = (short)f2u(sc);
    }
    *reinterpret_cast<short8*>(T + base) = o;
#pragma unroll
    for (int m = 32; m >= 1; m >>= 1) { sg += __shfl_xor(sg, m); sb += __shfl_xor(sb, m); }
    if (lane == 0) { gw[n] = sg; bw[n] = sb; }
}

// ---------------------------------------------------------------------------
// Legacy 128x128 MFMA GEMM (m97 structure) — fc2.  EPI=4: +bias +xf residual
// (token-major) and TRANSPOSED store to out (R6-proven epilogue).
// A split across two buffers at m-tile aSplit (h1c halves in ws).
// ---------------------------------------------------------------------------
template <int EPI>
__global__ __launch_bounds__(256) void gemm_bt(
    const u16* __restrict__ A, const u16* __restrict__ A2, int aSplit,
    const u16* __restrict__ Bt, const void* __restrict__ bias,
    u16* __restrict__ Cout, int Nt, int N, int K,
    const u16* __restrict__ xadd, void* __restrict__ outp, int tokOff,
    const int* __restrict__ dflag)
{
    const bool iF = dflag[0] != 0;
    __shared__ __align__(16) u16 As[2][128 * 32];
    __shared__ __align__(16) u16 Bs[2][128 * 32];
    const int bidf = blockIdx.x;
    const int xcd = bidf & 7;
    const int j = bidf >> 3;
    const int m_blk = (j / Nt) * 8 + xcd;
    const int n_blk = j % Nt;
    const int tid = threadIdx.x;
    const int lane = tid & 63, wid = tid >> 6;
    const int wm = wid >> 1, wn = wid & 1;
    const int quad = lane >> 4, l15 = lane & 15;

    floatx4 zero4 = {0.f, 0.f, 0.f, 0.f};
    floatx4 acc[4][4];
#pragma unroll
    for (int i = 0; i < 4; ++i)
#pragma unroll
        for (int jj = 0; jj < 4; ++jj) acc[i][jj] = zero4;

    const u16* Ab = (A2 && m_blk >= aSplit)
                  ? A2 + (size_t)(m_blk - aSplit) * 128 * K
                  : A + (size_t)m_blk * 128 * K;
    const u16* Bb = Bt + (size_t)n_blk * 128 * K;
    const int r0 = tid >> 2;
    const int k0o = (tid & 3) * 8;

    for (int kk = 0; kk < K; kk += 64) {
        if (kk) __syncthreads();
#pragma unroll
        for (int h = 0; h < 2; ++h) {
            const int kg = kk + h * 32 + k0o;
            char* dA = (char*)As[h] + wid * 1024;
            char* dB = (char*)Bs[h] + wid * 1024;
            __builtin_amdgcn_global_load_lds(AS1(Ab + (size_t)r0 * K + kg),        AS3(dA), 16, 0, 0);
            __builtin_amdgcn_global_load_lds(AS1(Ab + (size_t)(r0 + 64) * K + kg), AS3(dA + 4096), 16, 0, 0);
            __builtin_amdgcn_global_load_lds(AS1(Bb + (size_t)r0 * K + kg),        AS3(dB), 16, 0, 0);
            __builtin_amdgcn_global_load_lds(AS1(Bb + (size_t)(r0 + 64) * K + kg), AS3(dB + 4096), 16, 0, 0);
        }
        __syncthreads();
#pragma unroll
        for (int h = 0; h < 2; ++h) {
            short8 af[4], bfv[4];
#pragma unroll
            for (int i = 0; i < 4; ++i)
                af[i] = *reinterpret_cast<const short8*>(&As[h][(wm * 64 + i * 16 + l15) * 32 + quad * 8]);
#pragma unroll
            for (int jj = 0; jj < 4; ++jj)
                bfv[jj] = *reinterpret_cast<const short8*>(&Bs[h][(wn * 64 + jj * 16 + l15) * 32 + quad * 8]);
#pragma unroll
            for (int i = 0; i < 4; ++i)
#pragma unroll
                for (int jj = 0; jj < 4; ++jj)
                    acc[i][jj] = MFMA(af[i], bfv[jj], acc[i][jj]);
        }
    }

    const int m_base = m_blk * 128 + wm * 64 + quad * 4;
    const int n_base = n_blk * 128 + wn * 64 + l15;
#pragma unroll
    for (int i = 0; i < 4; ++i) {
#pragma unroll
        for (int jj = 0; jj < 4; ++jj) {
            const int n = n_base + jj * 16;
            float badd = 0.f;
            if constexpr (EPI >= 1) badd = ldf(bias, n, iF);
            if constexpr (EPI == 4) {
                float vv[4];
#pragma unroll
                for (int r = 0; r < 4; ++r) {
                    const int m = m_base + i * 16 + r;
                    vv[r] = acc[i][jj][r] + badd + u2f(xadd[(size_t)m * 512 + n]);
                }
                const size_t ob = (size_t)n * 32768 + tokOff + m_base + i * 16;
                if (iF) {
                    floatx4 v4 = {vv[0], vv[1], vv[2], vv[3]};
                    *reinterpret_cast<floatx4*>((float*)outp + ob) = v4;
                } else {
                    union { u16 a[4]; uint2 v; } pk;
#pragma unroll
                    for (int r = 0; r < 4; ++r) pk.a[r] = f2u(vv[r]);
                    *reinterpret_cast<uint2*>((u16*)outp + ob) = pk.v;
                }
            } else {
#pragma unroll
                for (int r = 0; r < 4; ++r) {
                    const int m = m_base + i * 16 + r;
                    float v = acc[i][jj][r] + badd;
                    if constexpr (EPI == 3) v = gelu_f(v);
                    Cout[(size_t)m * N + n] = f2u(v);
                }
            }
        }
    }
}

// ---------------------------------------------------------------------------
// 256x256 8-phase MFMA GEMM (T2+T3+T4+T5, m201-class schedule, plain HIP).
// EPI: 0 none, 2 +bias + token-major residual (proj, R9-proven),
// 5 LN-folded fc1: v = rstd[m]*(acc - mean[m]*gw[n]) + bw[n] + bias[n],
// GELU; output split across Cout/Cout2 at m-tile mSplit.
// ---------------------------------------------------------------------------
#define STG(slot, mat, kh, Gb, kcol) do {                                        \
    char* _d = (char*)&L[(slot)][(mat)][(kh)][0] + ldsofs;                       \
    __builtin_amdgcn_global_load_lds(AS1((Gb) + (size_t)srow0 * K + (kcol) + scol0),         AS3(_d),        16, 0, 0); \
    __builtin_amdgcn_global_load_lds(AS1((Gb) + (size_t)(srow0 + 128) * K + (kcol) + scol0), AS3(_d + 8192), 16, 0, 0); \
} while (0)

#define VMW(n) do { asm volatile("s_waitcnt vmcnt(" #n ")" ::: "memory");        \
                    __builtin_amdgcn_sched_barrier(0); } while (0)

#define PHASE(s, kh, nq, STAGE_STMT, WAIT_STMT) do {                             \
    const char* Au = (const char*)&L[(s)][0][(kh)][0];                           \
    const char* Bu = (const char*)&L[(s)][1][(kh)][0];                           \
    if ((nq) == 0) {                                                             \
        _Pragma("unroll")                                                        \
        for (int mf = 0; mf < 8; ++mf)                                           \
            af[mf] = *reinterpret_cast<const short8*>(Au + aoff[mf]);            \
    }                                                                            \
    short8 b0 = *reinterpret_cast<const short8*>(Bu + boff[nq][0]);              \
    short8 b1 = *reinterpret_cast<const short8*>(Bu + boff[nq][1]);              \
    STAGE_STMT;                                                                  \
    asm volatile("s_barrier" ::: "memory");                                      \
    asm volatile("s_waitcnt lgkmcnt(0)" ::: "memory");                           \
    __builtin_amdgcn_sched_barrier(0);                                           \
    __builtin_amdgcn_s_setprio(1);                                               \
    _Pragma("unroll")                                                            \
    for (int mf = 0; mf < 8; ++mf) {                                             \
        acc[mf][(nq) * 2]     = MFMA(af[mf], b0, acc[mf][(nq) * 2]);             \
        acc[mf][(nq) * 2 + 1] = MFMA(af[mf], b1, acc[mf][(nq) * 2 + 1]);         \
    }                                                                            \
    __builtin_amdgcn_s_setprio(0);                                               \
    WAIT_STMT;                                                                   \
    asm volatile("s_barrier" ::: "memory");                                      \
} while (0)

#define GROUP(g, W2, W4, S12, S34) do {                                          \
    const int _s = (g) & 1;                                                      \
    PHASE(_s, 0, 0, if (S12) STG(_s ^ 1, 0, 1, Ab, ((g) + 1) * 64 + 32), (void)0); \
    PHASE(_s, 0, 1, if (S12) STG(_s ^ 1, 1, 1, Bb, ((g) + 1) * 64 + 32), W2);    \
    PHASE(_s, 1, 0, if (S34) STG(_s,     0, 0, Ab, ((g) + 2) * 64),      (void)0); \
    PHASE(_s, 1, 1, if (S34) STG(_s,     1, 0, Bb, ((g) + 2) * 64),      W4);    \
} while (0)

template <int EPI>
__global__ __launch_bounds__(512, 2) void gemm256_bt(
    const u16* __restrict__ A, const u16* __restrict__ Bt,
    const void* __restrict__ bias,
    u16* __restrict__ Cout, u16* __restrict__ Cout2, int mSplit,
    int Nt, int N, int K,
    const u16* __restrict__ xadd,
    const float* __restrict__ s2, const float* __restrict__ gwv,
    const float* __restrict__ bwv,
    const int* __restrict__ dflag)
{
    const bool iF = dflag[0] != 0;
    __shared__ __align__(16) u16 L[2][2][2][8192];   // [slot][A/B][kh][256*32]
    const int bidf = blockIdx.x;
    const int xcd = bidf & 7;
    const int j = bidf >> 3;
    const int m_blk = (j / Nt) * 8 + xcd;
    const int n_blk = j % Nt;
    const int tid = threadIdx.x;
    const int lane = tid & 63, wid = tid >> 6;
    const int wm = wid >> 2, wn = wid & 3;
    const int quad = lane >> 4, l15 = lane & 15;

    const int srow0 = wid * 16 + (lane >> 2);
    const int scol0 = ((lane & 3) ^ ((srow0 >> 1) & 3)) * 8;
    const int ldsofs = wid * 1024;

    const u16* Ab = A + (size_t)m_blk * 256 * K;
    const u16* Bb = Bt + (size_t)n_blk * 256 * K;

    const int sq = (quad ^ ((l15 >> 1) & 3)) << 4;
    int aoff[8], boff[2][2];
#pragma unroll
    for (int mf = 0; mf < 8; ++mf)
        aoff[mf] = (wm * 128 + mf * 16 + l15) * 64 + sq;
#pragma unroll
    for (int nq = 0; nq < 2; ++nq)
#pragma unroll
        for (int jj = 0; jj < 2; ++jj)
            boff[nq][jj] = (wn * 64 + nq * 32 + jj * 16 + l15) * 64 + sq;

    floatx4 zero4 = {0.f, 0.f, 0.f, 0.f};
    floatx4 acc[8][4];
#pragma unroll
    for (int i = 0; i < 8; ++i)
#pragma unroll
        for (int jj = 0; jj < 4; ++jj) acc[i][jj] = zero4;
    short8 af[8];

    const int NG = K >> 6;

    STG(0, 0, 0, Ab, 0);
    STG(0, 1, 0, Bb, 0);
    STG(0, 0, 1, Ab, 32);
    STG(0, 1, 1, Bb, 32);
    STG(1, 0, 0, Ab, 64);
    STG(1, 1, 0, Bb, 64);
    VMW(8);
    asm volatile("s_barrier" ::: "memory");

    int g = 0;
    for (; g < NG - 2; ++g) GROUP(g, VMW(8), VMW(8), true, true);
    GROUP(g, VMW(8), VMW(4), true, false); ++g;
    GROUP(g, VMW(0), (void)0, false, false);

    u16* Co = Cout;
    int mOff = 0;
    if (EPI == 5 && Cout2 && m_blk >= mSplit) { Co = Cout2; mOff = mSplit * 256; }

    const int m0 = m_blk * 256 + wm * 128 + quad * 4;
    const int n0 = n_blk * 256 + wn * 64 + l15;
#pragma unroll
    for (int mf = 0; mf < 8; ++mf) {
        float mn[4], rs[4];
        if constexpr (EPI == 5) {
#pragma unroll
            for (int r = 0; r < 4; ++r) {
                const float2 st = reinterpret_cast<const float2*>(s2)[m0 + mf * 16 + r];
                mn[r] = st.x; rs[r] = st.y;
            }
        }
#pragma unroll
        for (int nf = 0; nf < 4; ++nf) {
            const int n = n0 + nf * 16;
            float badd = 0.f;
            if constexpr (EPI >= 1) badd = ldf(bias, n, iF);
            float gwn = 0.f, bwn = 0.f;
            if constexpr (EPI == 5) { gwn = gwv[n]; bwn = bwv[n]; }
#pragma unroll
            for (int r = 0; r < 4; ++r) {
                const int m = m0 + mf * 16 + r;
                float v;
                if constexpr (EPI == 5) {
                    v = rs[r] * (acc[mf][nf][r] - mn[r] * gwn) + bwn + badd;
                    v = gelu_f(v);
                } else {
                    v = acc[mf][nf][r] + badd;
                    if constexpr (EPI == 2) v += u2f(xadd[(size_t)m * 512 + n]);
                }
                Co[(size_t)(m - mOff) * N + n] = f2u(v);
            }
        }
    }
}

// ---------------------------------------------------------------------------
// CSWin window attention + fused LEPE (R10 structure, unchanged).
// ---------------------------------------------------------------------------
__global__ __launch_bounds__(256) void cswin_attn(
    const u16* __restrict__ qkv,
    const void* __restrict__ lepe0_w, const void* __restrict__ lepe0_b,
    const void* __restrict__ lepe1_w, const void* __restrict__ lepe1_b,
    u16* __restrict__ att, const int* __restrict__ dflag)
{
    const bool iF = dflag[0] != 0;
    __shared__ __align__(16) u16 q_s[4096];
    __shared__ __align__(16) u16 k_s[4096];
    __shared__ __align__(16) u16 vt_s[32 * 130];
    __shared__ float lw_s[32 * 9];
    __shared__ float lb_s[32];

    const int bid = blockIdx.x;
    const int branch = bid >> 11;
    const int rr = bid & 2047;
    const int win = rr >> 3, head = rr & 7;
    const int d = win >> 3, blk = win & 7;
    const int tid = threadIdx.x;
    const int lane = tid & 63, wid = tid >> 6;
    const int quad = lane >> 4, l15 = lane & 15;
    const int choff = branch * 256 + head * 32;
    const int dbase = d * 1024;

    const void* lw = branch ? lepe1_w : lepe0_w;
    const void* lbp = branch ? lepe1_b : lepe0_b;
    for (int i = tid; i < 288; i += 256) lw_s[i] = ldf(lw, head * 288 + i, iF);
    if (tid < 32) lb_s[tid] = ldf(lbp, head * 32 + tid, iF);

#pragma unroll
    for (int s = 0; s < 2; ++s) {
        int ch = tid + s * 256;
        int t = ch >> 2, e0 = (ch & 3) * 8;
        int l = branch ? (dbase + blk * 128 + t)
                       : (dbase + (t >> 2) * 32 + blk * 4 + (t & 3));
        size_t rowo = (size_t)l * 1536 + choff + e0;
        short8 qv = *reinterpret_cast<const short8*>(qkv + rowo);
        short8 kv = *reinterpret_cast<const short8*>(qkv + rowo + 512);
        short8 vv = *reinterpret_cast<const short8*>(qkv + rowo + 1024);
        const int sw = ((ch >> 3) & 3) << 3;     // row=ch>>2: ((row>>1)&3)<<3
        *reinterpret_cast<short8*>(&q_s[(ch * 8) ^ sw]) = qv;
        *reinterpret_cast<short8*>(&k_s[(ch * 8) ^ sw]) = kv;
#pragma unroll
        for (int j = 0; j < 8; ++j) vt_s[(e0 + j) * 130 + t] = (u16)vv[j];
    }
    __syncthreads();

    // ---- QK^T swapped: st[kt][qi] = St[k-tile kt][q-tile wid*2+qi] ----
    floatx4 zero4 = {0.f, 0.f, 0.f, 0.f};
    const int sq8 = (quad ^ ((l15 >> 1) & 3)) * 8;   // swizzled k-slot (u16)
    short8 qf[2];
#pragma unroll
    for (int qi = 0; qi < 2; ++qi)
        qf[qi] = *reinterpret_cast<const short8*>(&q_s[(wid * 32 + qi * 16 + l15) * 32 + sq8]);
    floatx4 st[8][2];
#pragma unroll
    for (int kt = 0; kt < 8; ++kt) { st[kt][0] = zero4; st[kt][1] = zero4; }
#pragma unroll
    for (int kt = 0; kt < 8; ++kt) {
        short8 kf = *reinterpret_cast<const short8*>(&k_s[(kt * 16 + l15) * 32 + sq8]);
        st[kt][0] = MFMA(kf, qf[0], st[kt][0]);
        st[kt][1] = MFMA(kf, qf[1], st[kt][1]);
    }
    // lane (quad,l15): st[kt][qi][r] = S[q = wid*32+qi*16+l15][k = kt*16+quad*4+r]

    // ---- softmax: lane-local over 32 regs + cross-quad reduce ----
    const float scale = 0.17677669529663687f;
    float inv[2];
#pragma unroll
    for (int qi = 0; qi < 2; ++qi) {
        float sum = 0.f;
#pragma unroll
        for (int kt = 0; kt < 8; ++kt)
#pragma unroll
            for (int r = 0; r < 4; ++r) {
                float v = __expf(st[kt][qi][r] * scale);
                st[kt][qi][r] = v;
                sum += v;
            }
        sum += __shfl_xor(sum, 16);
        sum += __shfl_xor(sum, 32);
        inv[qi] = 1.f / sum;
    }
    // pack P to bf16 pairs: pk[qi][kt][u] = (k even -> lo16)
    uint32_t pk[2][8][2];
#pragma unroll
    for (int qi = 0; qi < 2; ++qi)
#pragma unroll
        for (int kt = 0; kt < 8; ++kt)
#pragma unroll
            for (int u = 0; u < 2; ++u)
                pk[qi][kt][u] = (uint32_t)f2u(st[kt][qi][2 * u] * inv[qi])
                              | ((uint32_t)f2u(st[kt][qi][2 * u + 1] * inv[qi]) << 16);
    // stage 1 (xor-32): even slot -> A1 (from b5s=0 lane), odd slot -> B1
#pragma unroll
    for (int qi = 0; qi < 2; ++qi)
#pragma unroll
        for (int t = 0; t < 4; ++t)
#pragma unroll
            for (int u = 0; u < 2; ++u)
                pl32swap(pk[qi][2 * t][u], pk[qi][2 * t + 1][u]);

    // ---- PV: A-frag assembled in-register (stage 2: xor-16 + select) ----
    const uint32_t* v32 = (const uint32_t*)vt_s;
    const int hi4 = (lane >> 4) & 1;                  // lane bit4
    floatx4 oacc[2][2];
#pragma unroll
    for (int qi = 0; qi < 2; ++qi) { oacc[qi][0] = zero4; oacc[qi][1] = zero4; }
#pragma unroll
    for (int ks = 0; ks < 4; ++ks) {
        const int kq = ks * 16 + quad * 4;
        union { uint32_t w[4]; short8 s; } bv[2];
#pragma unroll
        for (int j = 0; j < 2; ++j) {
            const int chan = j * 16 + l15;
#pragma unroll
            for (int q = 0; q < 4; ++q) bv[j].w[q] = v32[chan * 65 + kq + q];
        }
#pragma unroll
        for (int qi = 0; qi < 2; ++qi) {
            const uint32_t a0 = pk[qi][2 * ks][0],     a1 = pk[qi][2 * ks][1];
            const uint32_t b0 = pk[qi][2 * ks + 1][0], b1 = pk[qi][2 * ks + 1][1];
            const uint32_t s0 = (uint32_t)__shfl_xor((int)a0, 16);
            const uint32_t s1 = (uint32_t)__shfl_xor((int)a1, 16);
            const uint32_t t0 = (uint32_t)__shfl_xor((int)b0, 16);
            const uint32_t t1 = (uint32_t)__shfl_xor((int)b1, 16);
            union { uint32_t w[4]; short8 s; } gw;
            gw.w[0] = hi4 ? t0 : a0;
            gw.w[1] = hi4 ? t1 : a1;
            gw.w[2] = hi4 ? b0 : s0;
            gw.w[3] = hi4 ? b1 : s1;
            oacc[qi][0] = MFMA(gw.s, bv[0].s, oacc[qi][0]);
            oacc[qi][1] = MFMA(gw.s, bv[1].s, oacc[qi][1]);
        }
    }
    // oacc[qi][j][r] = O[q = wid*32+qi*16+quad*4+r][ch = j*16+l15]

    // ---- LEPE epilogue: shared clamped b32 span loads per (ii,j,dy) ----
    const int Hs = branch ? 4 : 32;
    const int Wsz = branch ? 32 : 4;
    const int wsl = branch ? 5 : 2;
    const int wmask = Wsz - 1;
#pragma unroll
    for (int ii = 0; ii < 2; ++ii) {
        const int t0 = wid * 32 + ii * 16 + quad * 4;  // token of r=0
        const int hi0 = t0 >> wsl;
        const int w0 = t0 & wmask;
        const int y0 = (hi0 > 0) ? -1 : 0;
        const int y1 = (hi0 < Hs - 1) ? 1 : 0;
        const bool xm = (w0 > 0);
        const bool xp = (w0 + 4 < Wsz);
#pragma unroll
        for (int j = 0; j < 2; ++j) {
            const int e = j * 16 + l15;
            float val[4];
#pragma unroll
            for (int r = 0; r < 4; ++r) val[r] = oacc[ii][j][r] + lb_s[e];
            const uint32_t* vrow = v32 + e * 65;
            const float* wrow = &lw_s[e * 9];
            for (int dy = y0; dy <= y1; ++dy) {
                const int rowb = (hi0 + dy) << wsl;   // token base of conv row
                const int wlo = rowb >> 1;
                const int whi = wlo + (Wsz >> 1) - 1;
                const int wb = wlo + (w0 >> 1);       // word (w0, w0+1)
                int c0 = wb - 1; if (c0 < wlo) c0 = wlo;
                int c3 = wb + 2; if (c3 > whi) c3 = whi;
                const uint32_t u0 = vrow[c0];
                const uint32_t u1 = vrow[wb];
                const uint32_t u2 = vrow[wb + 1];
                const uint32_t u3 = vrow[c3];
                const float em1 = __uint_as_float(u0 & 0xffff0000u);
                const float f0 = __uint_as_float(u1 << 16);
                const float f1 = __uint_as_float(u1 & 0xffff0000u);
                const float f2 = __uint_as_float(u2 << 16);
                const float f3 = __uint_as_float(u2 & 0xffff0000u);
                const float f4 = __uint_as_float(u3 << 16);
                const float* w3 = wrow + (dy + 1) * 3;
                const float wl = w3[0], wc = w3[1], wp = w3[2];
                const float wl0 = xm ? wl : 0.f;
                const float wp3 = xp ? wp : 0.f;
                val[0] += wl0 * em1 + wc * f0 + wp * f1;
                val[1] += wl * f0 + wc * f1 + wp * f2;
                val[2] += wl * f1 + wc * f2 + wp * f3;
                val[3] += wl * f2 + wc * f3 + wp3 * f4;
            }
#pragma unroll
            for (int r = 0; r < 4; ++r) {
                const int t = t0 + r;
                const int l = branch ? (dbase + blk * 128 + t)
                                     : (dbase + (t >> 2) * 32 + blk * 4 + (t & 3));
                att[(size_t)l * 512 + choff + e] = f2u(val[r]);
            }
        }
    }
}

// ---------------------------------------------------------------------------
// Launch.  Workspace 104 MiB:
//   [0,2) qkvT [2,3) projT [3,5) fc1T [5,7) fc2T
//   [7,8): flag @+0, gw @+4K, bw @+16K, stats(float2 x 32768) @+32K
//   h1cA [8,40)   xf [40,72)   h1cB [72,104)   (qkvb [8,104) dead after attn)
//   d_out overlay: img [0,32) + xT [32,64) (dead after proj); final out
//   written by fc2 EPI=4 (residual + transposed store) directly.
//   LN2 folded into fc1: ln_stats + scalecol (scaled fc1T + gw/bw).
// ---------------------------------------------------------------------------
extern "C" void kernel_launch(void* const* d_in, const int* in_sizes, int n_in,
                              void* d_out, int out_size, void* d_ws, size_t ws_size,
                              hipStream_t stream)
{
    const void* x      = d_in[0];
    const void* n1g    = d_in[1];
    const void* n1b    = d_in[2];
    const void* qkv_w  = d_in[3];
    const void* l0w    = d_in[4];
    const void* l0b    = d_in[5];
    const void* l1w    = d_in[6];
    const void* l1b    = d_in[7];
    const void* proj_w = d_in[8];
    const void* proj_b = d_in[9];
    const void* n2g    = d_in[10];
    const void* n2b    = d_in[11];
    const void* fc1_w  = d_in[12];
    const void* fc1_b  = d_in[13];
    const void* fc2_w  = d_in[14];
    const void* fc2_b  = d_in[15];

    const size_t MB = 1ull << 20;
    if (ws_size < 104 * MB) return;

    char* w = (char*)d_ws;
    u16* qkvT  = (u16*)(w + 0 * MB);
    u16* projT = (u16*)(w + 2 * MB);
    u16* fc1T  = (u16*)(w + 3 * MB);
    u16* fc2T  = (u16*)(w + 5 * MB);
    int* flag  = (int*)(w + 7 * MB);
    float* gw  = (float*)(w + 7 * MB + 4096);
    float* bw  = (float*)(w + 7 * MB + 16384);
    float* stats = (float*)(w + 7 * MB + 32768);
    u16* qkvb  = (u16*)(w + 8 * MB);    // [8,104) dead after attn
    u16* h1cA  = (u16*)(w + 8 * MB);    // [8,40)  rows 0..8191
    u16* xf    = (u16*)(w + 40 * MB);   // [40,72)
    u16* h1cB  = (u16*)(w + 72 * MB);   // [72,104) rows 8192..16383
    u16* img   = (u16*)d_out;                       // d_out [0,32)
    u16* xT    = (u16*)d_out + 16777216;            // d_out [32,64)
    u16* attb  = (u16*)d_out;                       // d_out [0,32)

    const dim3 B(256);
    const dim3 B512(512);
    const u16* NUL = nullptr;
    u16* NULN = nullptr;
    const void* NULV = nullptr;
    const float* NULF = nullptr;

    detect_dtype<<<dim3(1), B, 0, stream>>>((const u16*)x, flag);

    // weight transposes to [N][K]
    transpose_k<0><<<dim3(24, 8), B, 0, stream>>>(qkv_w, qkvT, 0, 512, 1536, 512, NUL, flag, 1, 0);
    transpose_k<0><<<dim3(8, 8),  B, 0, stream>>>(proj_w, projT, 0, 512, 512, 512, NUL, flag, 1, 0);
    transpose_k<0><<<dim3(32, 8), B, 0, stream>>>(fc1_w, fc1T, 0, 512, 2048, 512, NUL, flag, 1, 0);
    transpose_k<0><<<dim3(8, 32), B, 0, stream>>>(fc2_w, fc2T, 0, 2048, 512, 2048, NUL, flag, 1, 0);
    // LN-fold precompute: scale fc1T rows by g[k] AND column sums gw/bw
    scalecol<<<dim3(512), B, 0, stream>>>(fc1T, n2g, n2b, gw, bw, flag);

    // fused transpose + LN1: x -> img [0,32) AND raw xT [32,64) (both bf16)
    tln64<<<dim3(512), B, 0, stream>>>(x, n1g, n1b, img, xT, flag);

    // qkv = img @ qkv_w   [32768][1536]   Mt=128, Nt=6
    gemm256_bt<0><<<dim3(128 * 6), B512, 0, stream>>>(img, qkvT, NULV, qkvb, NULN, 0, 6, 1536, 512, NUL, NULF, NULF, NULF, flag);

    cswin_attn<<<dim3(4096), B, 0, stream>>>(qkvb, l0w, l0b, l1w, l1b, attb, flag);

    // xf = att @ proj_w + proj_b + xT   (fused token-major residual)
    gemm256_bt<2><<<dim3(128 * 2), B512, 0, stream>>>(attb, projT, proj_b, xf, NULN, 0, 2, 512, 512, xT, NULF, NULF, NULF, flag);

    // LN2 stats for all tokens (mean,rstd per token of xf)
    ln_stats<<<dim3(8192), B, 0, stream>>>(xf, stats);

    // MLP in 2 chunks of 16384 tokens; LN folded into fc1; fc2 fuses +xf
    // residual and transposed store straight into d_out.
    for (int i = 0; i < 2; ++i) {
        const int tok0 = i * 16384;
        const size_t off = (size_t)tok0 * 512;
        gemm256_bt<5><<<dim3(64 * 8), B512, 0, stream>>>(xf + off, fc1T, fc1_b,
            h1cA, h1cB, 32, 8, 2048, 512, NUL,
            stats + (size_t)tok0 * 2, gw, bw, flag);
        gemm_bt<4><<<dim3(128 * 4), B, 0, stream>>>(h1cA, h1cB, 64, fc2T, fc2_b,
            NULN, 4, 512, 2048, xf + off, d_out, tok0, flag);
    }
}